// Round 1
// baseline (1898.713 us; speedup 1.0000x reference)
//
#include <hip/hip_runtime.h>
#include <math.h>

#define U_DIM 8001
#define I_DIM 16001
#define B_DIM 8192

// ---------------------------------------------------------------------------
// Kernel 1: per-user mean of nonzero ratings. One block per row.
// ub[u] = (count>0) ? sum/count : 0
// ---------------------------------------------------------------------------
__global__ void row_bias_kernel(const float* __restrict__ R, float* __restrict__ ub) {
    const int u = blockIdx.x;
    const float* row = R + (size_t)u * I_DIM;

    float s = 0.0f;
    int   c = 0;

    // Align to 16B: row byte base is u*64004, so element alignment phase = u & 3.
    const int pre  = (4 - (u & 3)) & 3;
    const int nvec = (I_DIM - pre) >> 2;          // float4 chunks
    const int vend = pre + (nvec << 2);

    // head scalars
    for (int i = threadIdx.x; i < pre; i += blockDim.x) {
        float v = row[i];
        s += v; c += (v != 0.0f);
    }
    // vector body
    const float4* rv = (const float4*)(row + pre);
    for (int i = threadIdx.x; i < nvec; i += blockDim.x) {
        float4 v = rv[i];
        s += v.x + v.y + v.z + v.w;
        c += (v.x != 0.0f) + (v.y != 0.0f) + (v.z != 0.0f) + (v.w != 0.0f);
    }
    // tail scalars
    for (int i = vend + threadIdx.x; i < I_DIM; i += blockDim.x) {
        float v = row[i];
        s += v; c += (v != 0.0f);
    }

    // wave64 reduce
    #pragma unroll
    for (int off = 32; off > 0; off >>= 1) {
        s += __shfl_down(s, off, 64);
        c += __shfl_down(c, off, 64);
    }
    __shared__ float ss[4];
    __shared__ int   sc[4];
    const int wid  = threadIdx.x >> 6;
    const int lane = threadIdx.x & 63;
    if (lane == 0) { ss[wid] = s; sc[wid] = c; }
    __syncthreads();
    if (threadIdx.x == 0) {
        float S = ss[0] + ss[1] + ss[2] + ss[3];
        int   C = sc[0] + sc[1] + sc[2] + sc[3];
        ub[u] = (C > 0) ? (S / (float)C) : 0.0f;
    }
}

// ---------------------------------------------------------------------------
// Kernel 2: one block per batch element b.
// score[b] = sum_u sim[user[b],u] * (R[u,item[b]] - ub[u])
// out[b]   = 5*sigmoid(score + user_bias[user[b]] + item_bias[item[b]] + gb)
// sim reads are coalesced (consecutive lanes -> consecutive u).
// R reads are a strided column gather; rely on lockstep u-sweep + L3 for reuse.
// ---------------------------------------------------------------------------
__global__ void dot_kernel(const int* __restrict__ user, const int* __restrict__ item,
                           const float* __restrict__ R, const float* __restrict__ S,
                           const float* __restrict__ user_bias,
                           const float* __restrict__ item_bias,
                           const float* __restrict__ gbias,
                           const float* __restrict__ ubfix,
                           float* __restrict__ out) {
    const int b   = blockIdx.x;
    const int usr = user[b];
    const int it  = item[b];

    const float* srow = S + (size_t)usr * U_DIM;

    float acc = 0.0f;
    for (int u = threadIdx.x; u < U_DIM; u += blockDim.x) {
        float sv = srow[u];                       // coalesced
        float rv = R[(size_t)u * I_DIM + it];     // strided column gather
        float ad = rv - ubfix[u];                 // ubfix: coalesced, L2-hot
        acc += sv * ad;
    }

    #pragma unroll
    for (int off = 32; off > 0; off >>= 1)
        acc += __shfl_down(acc, off, 64);

    __shared__ float ss[4];
    const int wid  = threadIdx.x >> 6;
    const int lane = threadIdx.x & 63;
    if (lane == 0) ss[wid] = acc;
    __syncthreads();

    if (threadIdx.x == 0) {
        float score = ss[0] + ss[1] + ss[2] + ss[3];
        float pred  = score + user_bias[usr] + item_bias[it] + gbias[0];
        out[b] = 5.0f / (1.0f + expf(-pred));
    }
}

// ---------------------------------------------------------------------------
extern "C" void kernel_launch(void* const* d_in, const int* in_sizes, int n_in,
                              void* d_out, int out_size, void* d_ws, size_t ws_size,
                              hipStream_t stream) {
    const int*   user = (const int*)  d_in[0];
    const int*   item = (const int*)  d_in[1];
    const float* R    = (const float*)d_in[2];
    const float* S    = (const float*)d_in[3];
    const float* ubia = (const float*)d_in[4];
    const float* ibia = (const float*)d_in[5];
    const float* gb   = (const float*)d_in[6];
    float* out   = (float*)d_out;
    float* ubfix = (float*)d_ws;      // U_DIM floats of scratch

    row_bias_kernel<<<U_DIM, 256, 0, stream>>>(R, ubfix);
    dot_kernel<<<B_DIM, 256, 0, stream>>>(user, item, R, S, ubia, ibia, gb, ubfix, out);
}